// Round 12
// baseline (366.063 us; speedup 1.0000x reference)
//
#include <hip/hip_runtime.h>
#include <hip/hip_bf16.h>

#define T_SEQ 2048
#define NHEAD 16
#define HDIM  64
#define CDIM  1024

typedef __attribute__((ext_vector_type(8))) short bf16x8;
typedef __attribute__((ext_vector_type(4))) short bf16x4;
typedef __attribute__((ext_vector_type(4))) float f32x4;

__device__ __forceinline__ unsigned short f2bf(float f) {
  union { __hip_bfloat16 h; unsigned short u; } c;
  c.h = __float2bfloat16(f);
  return c.u;
}

#define GLD16(g, l) __builtin_amdgcn_global_load_lds( \
  (const __attribute__((address_space(1))) void*)(g), \
  (__attribute__((address_space(3))) void*)(l), 16, 0, 0)

// ---------------- prep: weight transposes only (x-cast fused into qkv GEMM) ----------------
// blocks [0,3072): w_attn^T;  [3072,4096): w_proj^T
__global__ void prep_all(const float* __restrict__ wa, const float* __restrict__ wp,
                         unsigned short* __restrict__ wat, unsigned short* __restrict__ wpt) {
  __shared__ float tile[32][33];
  const int bid = blockIdx.x;
  const float* in; unsigned short* out; int R, C, bx, by;
  if (bid < 3072) { in = wa; out = wat; R = 1024; C = 3072; bx = bid % 96; by = bid / 96; }
  else            { in = wp; out = wpt; R = 1024; C = 1024; bx = (bid - 3072) % 32; by = (bid - 3072) / 32; }
  const int tx = threadIdx.x & 31, ty = threadIdx.x >> 5;
  const int c0 = bx * 32, r0 = by * 32;
#pragma unroll
  for (int i = 0; i < 32; i += 8)
    tile[ty + i][tx] = in[(size_t)(r0 + ty + i) * C + c0 + tx];
  __syncthreads();
#pragma unroll
  for (int i = 0; i < 32; i += 8)
    out[(size_t)(c0 + ty + i) * R + r0 + tx] = f2bf(tile[tx][ty + i]);
}

// ---------------- bf16 MFMA GEMM: C[M][N] = A[M][K] * BT[N][K]^T + bias ----------------
// 128x128 tile, BK=64, 4 waves (2x2), LDS slot-XOR swizzle, XCD-chunked block swizzle.
// AF32: A is f32 in global; staged via reg (2x float4 + cvt_pk + swizzled ds_write_b128).
template<int OUTF32, int AF32>
__global__ __launch_bounds__(256, 2)
void gemm_bt(const void* __restrict__ Ap, const unsigned short* __restrict__ BT,
             const float* __restrict__ bias, void* __restrict__ outp,
             int M, int N, int K) {
  const int tid = threadIdx.x;
  const int w = tid >> 6, lane = tid & 63;
  const int lg = lane >> 4, l15 = lane & 15;
  const int wr = w >> 1, wc = w & 1;

  const int nb = gridDim.x * gridDim.y;
  const int fid = blockIdx.y * gridDim.x + blockIdx.x;
  const int swz = (fid & 7) * (nb >> 3) + (fid >> 3);
  const int n0 = (swz % gridDim.x) * 128, m0 = (swz / gridDim.x) * 128;

  __shared__ unsigned short As[128 * 64];
  __shared__ unsigned short Bs[128 * 64];

  f32x4 acc[4][4] = {};

  for (int k0 = 0; k0 < K; k0 += 64) {
    __syncthreads();
#pragma unroll
    for (int i = 0; i < 4; ++i) {
      const int cb = i * 256 + w * 64;   // wave-uniform chunk base
      const int c  = cb + lane;
      const int row = c >> 3, s = c & 7;
      const int sg = s ^ (row & 7);      // pre-swizzled source slot
      if (AF32) {
        const float* A32 = (const float*)Ap;
        const float* p = A32 + (size_t)(m0 + row) * K + k0 + sg * 8;
        const float4 f0 = *(const float4*)p;
        const float4 f1 = *(const float4*)(p + 4);
        bf16x8 pk;
        pk[0] = (short)f2bf(f0.x); pk[1] = (short)f2bf(f0.y);
        pk[2] = (short)f2bf(f0.z); pk[3] = (short)f2bf(f0.w);
        pk[4] = (short)f2bf(f1.x); pk[5] = (short)f2bf(f1.y);
        pk[6] = (short)f2bf(f1.z); pk[7] = (short)f2bf(f1.w);
        *(bf16x8*)&As[row * 64 + s * 8] = pk;
      } else {
        const unsigned short* A16 = (const unsigned short*)Ap;
        GLD16(A16 + (size_t)(m0 + row) * K + k0 + sg * 8, (char*)As + cb * 16);
      }
      GLD16(BT + (size_t)(n0 + row) * K + k0 + sg * 8, (char*)Bs + cb * 16);
    }
    __syncthreads();
#pragma unroll
    for (int ks = 0; ks < 2; ++ks) {
      bf16x8 af[4], bfr[4];
#pragma unroll
      for (int mt = 0; mt < 4; ++mt) {
        const int row = wr * 64 + mt * 16 + l15;
        af[mt] = *(const bf16x8*)&As[row * 64 + (((ks * 4 + lg) ^ (l15 & 7)) << 3)];
      }
#pragma unroll
      for (int nt = 0; nt < 4; ++nt) {
        const int row = wc * 64 + nt * 16 + l15;
        bfr[nt] = *(const bf16x8*)&Bs[row * 64 + (((ks * 4 + lg) ^ (l15 & 7)) << 3)];
      }
#pragma unroll
      for (int mt = 0; mt < 4; ++mt)
#pragma unroll
        for (int nt = 0; nt < 4; ++nt)
          acc[mt][nt] = __builtin_amdgcn_mfma_f32_16x16x32_bf16(af[mt], bfr[nt], acc[mt][nt], 0, 0, 0);
    }
  }

#pragma unroll
  for (int mt = 0; mt < 4; ++mt) {
#pragma unroll
    for (int nt = 0; nt < 4; ++nt) {
      const int col = n0 + wc * 64 + nt * 16 + l15;
      const float bv = bias[col];
#pragma unroll
      for (int j = 0; j < 4; ++j) {
        const int row = m0 + wr * 64 + mt * 16 + lg * 4 + j;
        const float v = acc[mt][nt][j] + bv;
        if (OUTF32) ((float*)outp)[(size_t)row * N + col] = v;
        else ((unsigned short*)outp)[(size_t)row * N + col] = f2bf(v);
      }
    }
  }
}

// ---------------- causal flash attention v11: merged halves ----------------
// 512 threads = 8 waves; wave owns 16 q-rows of tile lo=pair AND 16 of hi=15-pair.
// One loop over 2(hi+1) KV64 tiles: stage once; fragment A active t<=2lo+1 shares
// all K/V ds_reads with B. Compute fragment-iters = 34/block (uniform).
// All v5-verified layouts: K row-permute+slot swizzle, V chunk swizzle, reg-only P.
#define EXPC 0.18033688f   /* 0.125 * log2(e) */
__global__ __launch_bounds__(512, 4)
void attn_causal11(const unsigned short* __restrict__ qkv, unsigned short* __restrict__ att) {
  const int tid = threadIdx.x;
  const int w = tid >> 6, lane = tid & 63;
  const int lg = lane >> 4, l15 = lane & 15;

  const int fid = blockIdx.x;                   // 0..511
  const int f2 = (fid & 7) * 64 + (fid >> 3);   // XCD-chunked remap (bijective)
  const int pair = f2 & 7, bh = f2 >> 3;
  const int b = bh >> 4, h = bh & 15;
  const int lo = pair, hi = 15 - pair;

  __shared__ unsigned short Kl[2][2][64][32];   // [buf][kc][ldsrow][el], slot+row permuted
  __shared__ unsigned short Vt[2][64][64];      // [buf][d][kv], chunk-swizzled

  const unsigned short* base = qkv + (size_t)b * T_SEQ * 3072;

  auto STAGE_K = [&](int kv0, int buf) {
    const int c = tid;                          // 512 chunks of 16B
    const int kc = c >> 8, slot = (c >> 2) & 63;
    const int s2 = (c & 3) ^ ((slot >> 1) & 3);
    const int v = (slot & 35) | ((slot & 8) << 1) | ((slot & 4) << 1) | ((slot & 16) >> 2);
    GLD16(base + (size_t)(kv0 + v) * 3072 + 1024 + h * 64 + kc * 32 + s2 * 8,
          (char*)&Kl[buf][0][0][0] + w * 1024);
  };

  bf16x4 vra, vrb;
  const int vkp = tid >> 4, vd4 = tid & 15;
  auto VLOAD = [&](int kv0) {
    const unsigned short* p = base + (size_t)(kv0 + 2 * vkp) * 3072 + 2048 + h * 64 + vd4 * 4;
    vra = *(const bf16x4*)p;
    vrb = *(const bf16x4*)(p + 3072);
  };
  auto VWRITE = [&](int buf) {
    const int ch = vkp >> 2, cl = (vkp & 3) * 2;
#pragma unroll
    for (int j = 0; j < 4; ++j) {
      const int r = vd4 * 4 + j;
      const unsigned int u = (unsigned short)vra[j] |
                             ((unsigned int)(unsigned short)vrb[j] << 16);
      *(unsigned int*)&Vt[buf][r][((ch ^ (r >> 3) ^ (r & 7)) << 3) + cl] = u;
    }
  };

  bf16x8 ones;
#pragma unroll
  for (int j = 0; j < 8; ++j) ones[j] = (short)0x3F80;   // bf16 1.0

  const int ntl = (hi + 1) << 1;                // KV64 tiles (18..32)
  const int qminA = __builtin_amdgcn_readfirstlane(lo * 128 + w * 16);
  const int qminB = __builtin_amdgcn_readfirstlane(hi * 128 + w * 16);
  const int qmeA = qminA + l15, qmeB = qminB + l15;

  bf16x8 qfA[2], qfB[2];
#pragma unroll
  for (int kc = 0; kc < 2; ++kc) {
    qfA[kc] = *(const bf16x8*)(base + (size_t)qmeA * 3072 + h * 64 + kc * 32 + lg * 8);
    qfB[kc] = *(const bf16x8*)(base + (size_t)qmeB * 3072 + h * 64 + kc * 32 + lg * 8);
  }

  f32x4 oaccA[4] = {}, oaccB[4] = {};
  f32x4 lsumA = {}, lsumB = {};
  float mA = -1e30f, mB = -1e30f;
  bf16x8 paA[2], paB[2];

  STAGE_K(0, 0);
  VLOAD(0);
  VWRITE(0);
  __syncthreads();

  for (int t = 0; t < ntl; ++t) {
    const int cur = t & 1, nxt = cur ^ 1;
    const bool pf = (t + 1) < ntl;
    if (pf) { STAGE_K((t + 1) << 6, nxt); VLOAD((t + 1) << 6); }
    const int kv0 = t << 6;
    const bool actA = kv0 <= qminA + 15;        // scalar (qmin in SGPR)
    const bool actB = kv0 <= qminB + 15;

    const int ksl = (lg ^ ((l15 >> 1) & 3)) * 8;
    f32x4 scA[4], scB[4];

    // ---- QK^T swapped (shared K reads when both fragments active) ----
    if (actA) {
      __builtin_amdgcn_s_setprio(1);
#pragma unroll
      for (int kg = 0; kg < 4; ++kg) {
        f32x4 sa = {}, sb = {};
#pragma unroll
        for (int kc = 0; kc < 2; ++kc) {
          bf16x8 kf = *(const bf16x8*)&Kl[cur][kc][kg * 16 + l15][ksl];
          sa = __builtin_amdgcn_mfma_f32_16x16x32_bf16(kf, qfA[kc], sa, 0, 0, 0);
          sb = __builtin_amdgcn_mfma_f32_16x16x32_bf16(kf, qfB[kc], sb, 0, 0, 0);
        }
        scA[kg] = sa; scB[kg] = sb;
      }
      __builtin_amdgcn_s_setprio(0);
    } else if (actB) {
      __builtin_amdgcn_s_setprio(1);
#pragma unroll
      for (int kg = 0; kg < 4; ++kg) {
        f32x4 sb = {};
#pragma unroll
        for (int kc = 0; kc < 2; ++kc) {
          bf16x8 kf = *(const bf16x8*)&Kl[cur][kc][kg * 16 + l15][ksl];
          sb = __builtin_amdgcn_mfma_f32_16x16x32_bf16(kf, qfB[kc], sb, 0, 0, 0);
        }
        scB[kg] = sb;
      }
      __builtin_amdgcn_s_setprio(0);
    }

    // ---- softmax fragment A ----
    if (actA) {
      if (kv0 + 63 > qminA) {
#pragma unroll
        for (int kg = 0; kg < 4; ++kg) {
          const int colb = kv0 + ((kg >> 1) << 5) + ((kg & 1) << 2) + lg * 8;
#pragma unroll
          for (int j = 0; j < 4; ++j)
            if (colb + j > qmeA) scA[kg][j] = -1e30f;
        }
      }
      float mx = -1e30f;
#pragma unroll
      for (int kg = 0; kg < 4; ++kg) {
        const float a = fmaxf(scA[kg][0], scA[kg][1]);
        const float c2 = fmaxf(scA[kg][2], scA[kg][3]);
        mx = fmaxf(mx, fmaxf(a, c2));
      }
      if (__any(mx > mA + 55.4f)) {
        float mw = fmaxf(mx, __shfl_xor(mx, 16));
        mw = fmaxf(mw, __shfl_xor(mw, 32));
        const float mnew = fmaxf(mA, mw);
        const float alc = exp2f((mA - mnew) * EXPC);
        mA = mnew;
        float alq[4];
#pragma unroll
        for (int j = 0; j < 4; ++j)
          alq[j] = __shfl(alc, (lane & 48) | (lg * 4 + j));
#pragma unroll
        for (int j = 0; j < 4; ++j) {
          lsumA[j] *= alq[j];
#pragma unroll
          for (int dt = 0; dt < 4; ++dt) oaccA[dt][j] *= alq[j];
        }
      }
      const float mc = mA * EXPC;
#pragma unroll
      for (int kg = 0; kg < 4; ++kg) {
        const int ks = kg >> 1, off = (kg & 1) * 4;
#pragma unroll
        for (int j = 0; j < 4; ++j) {
          const float p = exp2f(__fmaf_rn(scA[kg][j], EXPC, -mc));
          paA[ks][off + j] = (short)f2bf(p);
        }
      }
    }

    // ---- softmax fragment B ----
    if (actB) {
      if (kv0 + 63 > qminB) {
#pragma unroll
        for (int kg = 0; kg < 4; ++kg) {
          const int colb = kv0 + ((kg >> 1) << 5) + ((kg & 1) << 2) + lg * 8;
#pragma unroll
          for (int j = 0; j < 4; ++j)
            if (colb + j > qmeB) scB[kg][j] = -1e30f;
        }
      }
      float mx = -1e30f;
#pragma unroll
      for (int kg = 0; kg < 4; ++kg) {
        const float a = fmaxf(scB[kg][0], scB[kg][1]);
        const float c2 = fmaxf(scB[kg][2], scB[kg][3]);
        mx = fmaxf(mx, fmaxf(a, c2));
      }
      if (__any(mx > mB + 55.4f)) {
        float mw = fmaxf(mx, __shfl_xor(mx, 16));
        mw = fmaxf(mw, __shfl_xor(mw, 32));
        const float mnew = fmaxf(mB, mw);
        const float alc = exp2f((mB - mnew) * EXPC);
        mB = mnew;
        float alq[4];
#pragma unroll
        for (int j = 0; j < 4; ++j)
          alq[j] = __shfl(alc, (lane & 48) | (lg * 4 + j));
#pragma unroll
        for (int j = 0; j < 4; ++j) {
          lsumB[j] *= alq[j];
#pragma unroll
          for (int dt = 0; dt < 4; ++dt) oaccB[dt][j] *= alq[j];
        }
      }
      const float mc = mB * EXPC;
#pragma unroll
      for (int kg = 0; kg < 4; ++kg) {
        const int ks = kg >> 1, off = (kg & 1) * 4;
#pragma unroll
        for (int j = 0; j < 4; ++j) {
          const float p = exp2f(__fmaf_rn(scB[kg][j], EXPC, -mc));
          paB[ks][off + j] = (short)f2bf(p);
        }
      }
    }

    // ---- lsum + PV (shared V reads when both active) ----
    if (actA) {
      __builtin_amdgcn_s_setprio(1);
      lsumA = __builtin_amdgcn_mfma_f32_16x16x32_bf16(paA[0], ones, lsumA, 0, 0, 0);
      lsumA = __builtin_amdgcn_mfma_f32_16x16x32_bf16(paA[1], ones, lsumA, 0, 0, 0);
      lsumB = __builtin_amdgcn_mfma_f32_16x16x32_bf16(paB[0], ones, lsumB, 0, 0, 0);
      lsumB = __builtin_amdgcn_mfma_f32_16x16x32_bf16(paB[1], ones, lsumB, 0, 0, 0);
#pragma unroll
      for (int dt = 0; dt < 4; ++dt) {
        f32x4 oa = oaccA[dt], ob = oaccB[dt];
        const int d = dt * 16 + l15;
        const int gx = (d >> 3) ^ (d & 7);
#pragma unroll
        for (int ks = 0; ks < 2; ++ks) {
          bf16x8 vb = *(const bf16x8*)&Vt[cur][d][((ks * 4 + lg) ^ gx) << 3];
          oa = __builtin_amdgcn_mfma_f32_16x16x32_bf16(paA[ks], vb, oa, 0, 0, 0);
          ob = __builtin_amdgcn_mfma_f32_16x16x32_bf16(paB[ks], vb, ob, 0, 0, 0);
        }
        oaccA[dt] = oa; oaccB[dt] = ob;
      }
      __builtin_amdgcn_s_setprio(0);
    } else if (actB) {
      __builtin_amdgcn_s_setprio(1);
      lsumB = __builtin_amdgcn_mfma_f32_16x16x32_bf16(paB[0], ones, lsumB, 0, 0, 0);
      lsumB = __builtin_amdgcn_mfma_f32_16x16x32_bf16(paB[1], ones, lsumB, 0, 0, 0);
#pragma unroll
      for (int dt = 0; dt < 4; ++dt) {
        f32x4 ob = oaccB[dt];
        const int d = dt * 16 + l15;
        const int gx = (d >> 3) ^ (d & 7);
#pragma unroll
        for (int ks = 0; ks < 2; ++ks) {
          bf16x8 vb = *(const bf16x8*)&Vt[cur][d][((ks * 4 + lg) ^ gx) << 3];
          ob = __builtin_amdgcn_mfma_f32_16x16x32_bf16(paB[ks], vb, ob, 0, 0, 0);
        }
        oaccB[dt] = ob;
      }
      __builtin_amdgcn_s_setprio(0);
    }

    if (pf) VWRITE(nxt);
    __syncthreads();   // drains vmcnt (K gld_lds) + lgkm (V writes); swap buffers
  }

  // ---- epilogue: normalize via rcp, store both fragments ----
  {
    f32x4 invA, invB;
#pragma unroll
    for (int j = 0; j < 4; ++j) {
      invA[j] = __builtin_amdgcn_rcpf(lsumA[j]);
      invB[j] = __builtin_amdgcn_rcpf(lsumB[j]);
    }
#pragma unroll
    for (int dt = 0; dt < 4; ++dt)
#pragma unroll
      for (int j = 0; j < 4; ++j) {
        const int qa = qminA + lg * 4 + j;
        const int qb = qminB + lg * 4 + j;
        att[(size_t)(b * T_SEQ + qa) * CDIM + h * HDIM + dt * 16 + l15] =
            f2bf(oaccA[dt][j] * invA[j]);
        att[(size_t)(b * T_SEQ + qb) * CDIM + h * HDIM + dt * 16 + l15] =
            f2bf(oaccB[dt][j] * invB[j]);
      }
  }
}

// ---------------- launcher ----------------
extern "C" void kernel_launch(void* const* d_in, const int* in_sizes, int n_in,
                              void* d_out, int out_size, void* d_ws, size_t ws_size,
                              hipStream_t stream) {
  const float* x      = (const float*)d_in[0];
  const float* w_attn = (const float*)d_in[1];
  const float* b_attn = (const float*)d_in[2];
  const float* w_proj = (const float*)d_in[3];
  const float* b_proj = (const float*)d_in[4];

  char* ws = (char*)d_ws;
  unsigned short* wat = (unsigned short*)(ws + 16777216);    // 3072*1024 bf16 (w_attn^T)
  unsigned short* wpt = (unsigned short*)(ws + 23068672);    // 1024*1024 bf16 (w_proj^T)
  unsigned short* qkv = (unsigned short*)(ws + 25165824);    // 8192*3072 bf16
  unsigned short* att = (unsigned short*)(ws + 75497472);    // 8192*1024 bf16

  prep_all<<<dim3(4096), 256, 0, stream>>>(w_attn, w_proj, wat, wpt);
  gemm_bt<0, 1><<<dim3(24, 64), 256, 0, stream>>>((const void*)x, wat, b_attn, (void*)qkv, 8192, 3072, 1024);
  attn_causal11<<<dim3(512), 512, 0, stream>>>(qkv, att);
  gemm_bt<1, 0><<<dim3(8, 64), 256, 0, stream>>>((const void*)att, wpt, b_proj, d_out, 8192, 1024, 1024);
}

// Round 13
// 174.351 us; speedup vs baseline: 2.0996x; 2.0996x over previous
//
#include <hip/hip_runtime.h>
#include <hip/hip_bf16.h>

#define T_SEQ 2048
#define NHEAD 16
#define HDIM  64
#define CDIM  1024

typedef __attribute__((ext_vector_type(8))) short bf16x8;
typedef __attribute__((ext_vector_type(4))) short bf16x4;
typedef __attribute__((ext_vector_type(4))) float f32x4;

__device__ __forceinline__ unsigned short f2bf(float f) {
  union { __hip_bfloat16 h; unsigned short u; } c;
  c.h = __float2bfloat16(f);
  return c.u;
}

#define GLD16(g, l) __builtin_amdgcn_global_load_lds( \
  (const __attribute__((address_space(1))) void*)(g), \
  (__attribute__((address_space(3))) void*)(l), 16, 0, 0)

// ---------------- prep: weight transposes only (x-cast fused into qkv GEMM) ----------------
__global__ void prep_all(const float* __restrict__ wa, const float* __restrict__ wp,
                         unsigned short* __restrict__ wat, unsigned short* __restrict__ wpt) {
  __shared__ float tile[32][33];
  const int bid = blockIdx.x;
  const float* in; unsigned short* out; int R, C, bx, by;
  if (bid < 3072) { in = wa; out = wat; R = 1024; C = 3072; bx = bid % 96; by = bid / 96; }
  else            { in = wp; out = wpt; R = 1024; C = 1024; bx = (bid - 3072) % 32; by = (bid - 3072) / 32; }
  const int tx = threadIdx.x & 31, ty = threadIdx.x >> 5;
  const int c0 = bx * 32, r0 = by * 32;
#pragma unroll
  for (int i = 0; i < 32; i += 8)
    tile[ty + i][tx] = in[(size_t)(r0 + ty + i) * C + c0 + tx];
  __syncthreads();
#pragma unroll
  for (int i = 0; i < 32; i += 8)
    out[(size_t)(c0 + ty + i) * R + r0 + tx] = f2bf(tile[tx][ty + i]);
}

// ---------------- bf16 MFMA GEMM: C[M][N] = A[M][K] * BT[N][K]^T + bias ----------------
// 128x128 tile, BK=64, 4 waves (2x2), LDS slot-XOR swizzle, XCD-chunked block swizzle.
// AF32: A is f32 in global; staged via reg (2x float4 + cvt + swizzled ds_write_b128).
template<int OUTF32, int AF32>
__global__ __launch_bounds__(256, 2)
void gemm_bt(const void* __restrict__ Ap, const unsigned short* __restrict__ BT,
             const float* __restrict__ bias, void* __restrict__ outp,
             int M, int N, int K) {
  const int tid = threadIdx.x;
  const int w = tid >> 6, lane = tid & 63;
  const int lg = lane >> 4, l15 = lane & 15;
  const int wr = w >> 1, wc = w & 1;

  const int nb = gridDim.x * gridDim.y;
  const int fid = blockIdx.y * gridDim.x + blockIdx.x;
  const int swz = (fid & 7) * (nb >> 3) + (fid >> 3);
  const int n0 = (swz % gridDim.x) * 128, m0 = (swz / gridDim.x) * 128;

  __shared__ unsigned short As[128 * 64];
  __shared__ unsigned short Bs[128 * 64];

  f32x4 acc[4][4] = {};

  for (int k0 = 0; k0 < K; k0 += 64) {
    __syncthreads();
#pragma unroll
    for (int i = 0; i < 4; ++i) {
      const int cb = i * 256 + w * 64;   // wave-uniform chunk base
      const int c  = cb + lane;
      const int row = c >> 3, s = c & 7;
      const int sg = s ^ (row & 7);      // pre-swizzled source slot
      if (AF32) {
        const float* A32 = (const float*)Ap;
        const float* p = A32 + (size_t)(m0 + row) * K + k0 + sg * 8;
        const float4 f0 = *(const float4*)p;
        const float4 f1 = *(const float4*)(p + 4);
        bf16x8 pk;
        pk[0] = (short)f2bf(f0.x); pk[1] = (short)f2bf(f0.y);
        pk[2] = (short)f2bf(f0.z); pk[3] = (short)f2bf(f0.w);
        pk[4] = (short)f2bf(f1.x); pk[5] = (short)f2bf(f1.y);
        pk[6] = (short)f2bf(f1.z); pk[7] = (short)f2bf(f1.w);
        *(bf16x8*)&As[row * 64 + s * 8] = pk;
      } else {
        const unsigned short* A16 = (const unsigned short*)Ap;
        GLD16(A16 + (size_t)(m0 + row) * K + k0 + sg * 8, (char*)As + cb * 16);
      }
      GLD16(BT + (size_t)(n0 + row) * K + k0 + sg * 8, (char*)Bs + cb * 16);
    }
    __syncthreads();
#pragma unroll
    for (int ks = 0; ks < 2; ++ks) {
      bf16x8 af[4], bfr[4];
#pragma unroll
      for (int mt = 0; mt < 4; ++mt) {
        const int row = wr * 64 + mt * 16 + l15;
        af[mt] = *(const bf16x8*)&As[row * 64 + (((ks * 4 + lg) ^ (l15 & 7)) << 3)];
      }
#pragma unroll
      for (int nt = 0; nt < 4; ++nt) {
        const int row = wc * 64 + nt * 16 + l15;
        bfr[nt] = *(const bf16x8*)&Bs[row * 64 + (((ks * 4 + lg) ^ (l15 & 7)) << 3)];
      }
#pragma unroll
      for (int mt = 0; mt < 4; ++mt)
#pragma unroll
        for (int nt = 0; nt < 4; ++nt)
          acc[mt][nt] = __builtin_amdgcn_mfma_f32_16x16x32_bf16(af[mt], bfr[nt], acc[mt][nt], 0, 0, 0);
    }
  }

#pragma unroll
  for (int mt = 0; mt < 4; ++mt) {
#pragma unroll
    for (int nt = 0; nt < 4; ++nt) {
      const int col = n0 + wc * 64 + nt * 16 + l15;
      const float bv = bias[col];
#pragma unroll
      for (int j = 0; j < 4; ++j) {
        const int row = m0 + wr * 64 + mt * 16 + lg * 4 + j;
        const float v = acc[mt][nt][j] + bv;
        if (OUTF32) ((float*)outp)[(size_t)row * N + col] = v;
        else ((unsigned short*)outp)[(size_t)row * N + col] = f2bf(v);
      }
    }
  }
}

// ---------------- causal flash attention (v5 exact, proven 87.4 us) ----------------
// 512 threads = 8 waves x 16 q-rows; in-block pairing {p,15-p}: uniform 34 KV64 iters.
// K rows bit-permuted in LDS so swapped-QK^T output == PV A-fragment (reg-only P);
// lsum via ones-MFMA in O layout; scalarized mask; K slot swizzle; V chunk swizzle.
#define EXPC 0.18033688f   /* 0.125 * log2(e) */
__global__ __launch_bounds__(512, 4)
void attn_causal5(const unsigned short* __restrict__ qkv, unsigned short* __restrict__ att) {
  const int tid = threadIdx.x;
  const int w = tid >> 6, lane = tid & 63;
  const int lg = lane >> 4, l15 = lane & 15;

  const int fid = blockIdx.x;                   // 0..511
  const int f2 = (fid & 7) * 64 + (fid >> 3);   // XCD-chunked remap (bijective)
  const int pair = f2 & 7, bh = f2 >> 3;
  const int b = bh >> 4, h = bh & 15;

  __shared__ unsigned short Kl[2][2][64][32];   // [buf][kc][ldsrow][el], slot+row permuted
  __shared__ unsigned short Vt[2][64][64];      // [buf][d][kv], chunk-swizzled

  const unsigned short* base = qkv + (size_t)b * T_SEQ * 3072;

  auto STAGE_K = [&](int kv0, int buf) {
    const int c = tid;                          // 512 chunks of 16B
    const int kc = c >> 8, slot = (c >> 2) & 63;
    const int s2 = (c & 3) ^ ((slot >> 1) & 3);
    const int v = (slot & 35) | ((slot & 8) << 1) | ((slot & 4) << 1) | ((slot & 16) >> 2);
    GLD16(base + (size_t)(kv0 + v) * 3072 + 1024 + h * 64 + kc * 32 + s2 * 8,
          (char*)&Kl[buf][0][0][0] + w * 1024);
  };

  bf16x4 vra, vrb;
  const int vkp = tid >> 4, vd4 = tid & 15;
  auto VLOAD = [&](int kv0) {
    const unsigned short* p = base + (size_t)(kv0 + 2 * vkp) * 3072 + 2048 + h * 64 + vd4 * 4;
    vra = *(const bf16x4*)p;
    vrb = *(const bf16x4*)(p + 3072);
  };
  auto VWRITE = [&](int buf) {
    const int ch = vkp >> 2, cl = (vkp & 3) * 2;
#pragma unroll
    for (int j = 0; j < 4; ++j) {
      const int r = vd4 * 4 + j;
      const unsigned int u = (unsigned short)vra[j] |
                             ((unsigned int)(unsigned short)vrb[j] << 16);
      *(unsigned int*)&Vt[buf][r][((ch ^ (r >> 3) ^ (r & 7)) << 3) + cl] = u;
    }
  };

  bf16x8 ones;
#pragma unroll
  for (int j = 0; j < 8; ++j) ones[j] = (short)0x3F80;   // bf16 1.0

  for (int half = 0; half < 2; ++half) {
    const int qt = half ? (15 - pair) : pair;
    const int q0 = qt << 7;
    const int ntl = (qt + 1) << 1;              // KV64 tiles
    const int qminS = __builtin_amdgcn_readfirstlane(q0 + w * 16);
    const int qme = qminS + l15;

    bf16x8 qf[2];
#pragma unroll
    for (int kc = 0; kc < 2; ++kc)
      qf[kc] = *(const bf16x8*)(base + (size_t)qme * 3072 + h * 64 + kc * 32 + lg * 8);

    f32x4 oacc[4] = {};
    f32x4 lsum = {};
    float m = -1e30f;

    STAGE_K(0, 0);
    VLOAD(0);
    VWRITE(0);
    __syncthreads();

    for (int t = 0; t < ntl; ++t) {
      const int cur = t & 1, nxt = cur ^ 1;
      const bool pf = (t + 1) < ntl;
      if (pf) { STAGE_K((t + 1) << 6, nxt); VLOAD((t + 1) << 6); }
      const int kv0 = t << 6;

      if (kv0 <= qminS + 15) {                  // wave has unmasked work
        const int ksl = (lg ^ ((l15 >> 1) & 3)) * 8;
        f32x4 sc[4];
        __builtin_amdgcn_s_setprio(1);
#pragma unroll
        for (int kg = 0; kg < 4; ++kg) {
          f32x4 s = {};
#pragma unroll
          for (int kc = 0; kc < 2; ++kc) {
            bf16x8 kf = *(const bf16x8*)&Kl[cur][kc][kg * 16 + l15][ksl];
            s = __builtin_amdgcn_mfma_f32_16x16x32_bf16(kf, qf[kc], s, 0, 0, 0);
          }
          sc[kg] = s;
        }
        __builtin_amdgcn_s_setprio(0);

        // ---- mask (diagonal tiles only, scalar-guarded) ----
        float sv[4][4];
        if (kv0 + 63 > qminS) {
#pragma unroll
          for (int kg = 0; kg < 4; ++kg) {
            const int colb = kv0 + ((kg >> 1) << 5) + ((kg & 1) << 2) + lg * 8;
#pragma unroll
            for (int j = 0; j < 4; ++j)
              sv[kg][j] = (colb + j <= qme) ? sc[kg][j] : -1e30f;
          }
        } else {
#pragma unroll
          for (int kg = 0; kg < 4; ++kg)
#pragma unroll
            for (int j = 0; j < 4; ++j) sv[kg][j] = sc[kg][j];
        }

        // ---- tree max ----
        float mx = -1e30f;
#pragma unroll
        for (int kg = 0; kg < 4; ++kg) {
          const float a = fmaxf(sv[kg][0], sv[kg][1]);
          const float c2 = fmaxf(sv[kg][2], sv[kg][3]);
          mx = fmaxf(mx, fmaxf(a, c2));
        }

        // ---- defer-max rescale (rare) ----
        if (__any(mx > m + 55.4f)) {
          float mw = fmaxf(mx, __shfl_xor(mx, 16));
          mw = fmaxf(mw, __shfl_xor(mw, 32));
          const float mnew = fmaxf(m, mw);
          const float alc = exp2f((m - mnew) * EXPC);
          m = mnew;
          float alq[4];
#pragma unroll
          for (int j = 0; j < 4; ++j)
            alq[j] = __shfl(alc, (lane & 48) | (lg * 4 + j));
#pragma unroll
          for (int j = 0; j < 4; ++j) {
            lsum[j] *= alq[j];
#pragma unroll
            for (int dt = 0; dt < 4; ++dt) oacc[dt][j] *= alq[j];
          }
        }

        // ---- exp -> PV A-fragments (registers, same lane) ----
        const float mc = m * EXPC;
        bf16x8 pa[2];
#pragma unroll
        for (int kg = 0; kg < 4; ++kg) {
          const int ks = kg >> 1, off = (kg & 1) * 4;
#pragma unroll
          for (int j = 0; j < 4; ++j) {
            const float p = exp2f(__fmaf_rn(sv[kg][j], EXPC, -mc));
            pa[ks][off + j] = (short)f2bf(p);
          }
        }

        // ---- lsum via ones-MFMA + PV ----
        __builtin_amdgcn_s_setprio(1);
        lsum = __builtin_amdgcn_mfma_f32_16x16x32_bf16(pa[0], ones, lsum, 0, 0, 0);
        lsum = __builtin_amdgcn_mfma_f32_16x16x32_bf16(pa[1], ones, lsum, 0, 0, 0);
#pragma unroll
        for (int dt = 0; dt < 4; ++dt) {
          f32x4 o = oacc[dt];
          const int d = dt * 16 + l15;
          const int gx = (d >> 3) ^ (d & 7);    // V chunk swizzle
#pragma unroll
          for (int ks = 0; ks < 2; ++ks) {
            bf16x8 vb = *(const bf16x8*)&Vt[cur][d][((ks * 4 + lg) ^ gx) << 3];
            o = __builtin_amdgcn_mfma_f32_16x16x32_bf16(pa[ks], vb, o, 0, 0, 0);
          }
          oacc[dt] = o;
        }
        __builtin_amdgcn_s_setprio(0);
      }

      if (pf) VWRITE(nxt);
      __syncthreads();   // drains vmcnt (K gld_lds) + lgkm (V writes); swap buffers
    }

    // ---- epilogue: normalize via rcp, store ----
    f32x4 inv;
#pragma unroll
    for (int j = 0; j < 4; ++j) inv[j] = __builtin_amdgcn_rcpf(lsum[j]);
#pragma unroll
    for (int dt = 0; dt < 4; ++dt)
#pragma unroll
      for (int j = 0; j < 4; ++j) {
        const int q = qminS + lg * 4 + j;
        att[(size_t)(b * T_SEQ + q) * CDIM + h * HDIM + dt * 16 + l15] =
            f2bf(oacc[dt][j] * inv[j]);
      }
  }
}

// ---------------- launcher ----------------
extern "C" void kernel_launch(void* const* d_in, const int* in_sizes, int n_in,
                              void* d_out, int out_size, void* d_ws, size_t ws_size,
                              hipStream_t stream) {
  const float* x      = (const float*)d_in[0];
  const float* w_attn = (const float*)d_in[1];
  const float* b_attn = (const float*)d_in[2];
  const float* w_proj = (const float*)d_in[3];
  const float* b_proj = (const float*)d_in[4];

  char* ws = (char*)d_ws;
  unsigned short* wat = (unsigned short*)(ws + 16777216);    // 3072*1024 bf16 (w_attn^T)
  unsigned short* wpt = (unsigned short*)(ws + 23068672);    // 1024*1024 bf16 (w_proj^T)
  unsigned short* qkv = (unsigned short*)(ws + 25165824);    // 8192*3072 bf16
  unsigned short* att = (unsigned short*)(ws + 75497472);    // 8192*1024 bf16

  prep_all<<<dim3(4096), 256, 0, stream>>>(w_attn, w_proj, wat, wpt);
  gemm_bt<0, 1><<<dim3(24, 64), 256, 0, stream>>>((const void*)x, wat, b_attn, (void*)qkv, 8192, 3072, 1024);
  attn_causal5<<<dim3(512), 512, 0, stream>>>(qkv, att);
  gemm_bt<1, 0><<<dim3(8, 64), 256, 0, stream>>>((const void*)att, wpt, b_proj, d_out, 8192, 1024, 1024);
}

// Round 14
// 171.879 us; speedup vs baseline: 2.1298x; 1.0144x over previous
//
#include <hip/hip_runtime.h>
#include <hip/hip_bf16.h>

#define T_SEQ 2048
#define NHEAD 16
#define HDIM  64
#define CDIM  1024

typedef __attribute__((ext_vector_type(8))) short bf16x8;
typedef __attribute__((ext_vector_type(4))) short bf16x4;
typedef __attribute__((ext_vector_type(4))) float f32x4;

__device__ __forceinline__ unsigned short f2bf(float f) {
  union { __hip_bfloat16 h; unsigned short u; } c;
  c.h = __float2bfloat16(f);
  return c.u;
}

#define GLD16(g, l) __builtin_amdgcn_global_load_lds( \
  (const __attribute__((address_space(1))) void*)(g), \
  (__attribute__((address_space(3))) void*)(l), 16, 0, 0)

// ---------------- merged prep: x->bf16 cast + both weight transposes ----------------
// blocks [0,8192): cvt x (float4 each);  [8192,11264): w_attn^T;  [11264,12288): w_proj^T
__global__ void prep_all(const float* __restrict__ x, const float* __restrict__ wa,
                         const float* __restrict__ wp, unsigned short* __restrict__ xb,
                         unsigned short* __restrict__ wat, unsigned short* __restrict__ wpt) {
  __shared__ float tile[32][33];
  const int bid = blockIdx.x;
  if (bid < 8192) {
    const int i = bid * 256 + threadIdx.x;
    const float4 v = ((const float4*)x)[i];
    ushort4 o;
    o.x = f2bf(v.x); o.y = f2bf(v.y); o.z = f2bf(v.z); o.w = f2bf(v.w);
    ((ushort4*)xb)[i] = o;
    return;
  }
  const float* in; unsigned short* out; int R, C, bx, by;
  if (bid < 11264) { in = wa; out = wat; R = 1024; C = 3072; bx = (bid - 8192) % 96; by = (bid - 8192) / 96; }
  else             { in = wp; out = wpt; R = 1024; C = 1024; bx = (bid - 11264) % 32; by = (bid - 11264) / 32; }
  const int tx = threadIdx.x & 31, ty = threadIdx.x >> 5;
  const int c0 = bx * 32, r0 = by * 32;
#pragma unroll
  for (int i = 0; i < 32; i += 8)
    tile[ty + i][tx] = in[(size_t)(r0 + ty + i) * C + c0 + tx];
  __syncthreads();
#pragma unroll
  for (int i = 0; i < 32; i += 8)
    out[(size_t)(c0 + ty + i) * R + r0 + tx] = f2bf(tile[tx][ty + i]);
}

// ---------------- bf16 MFMA GEMM: C[M][N] = A[M][K] * BT[N][K]^T + bias ----------------
// 128x128 tile, BK=64 (half the barrier-drain events of BK=32), 4 waves (2x2).
// LDS slot-XOR swizzle: stage fetches global slot s^(row&7) into phys slot s;
// frag reads use phys = (ks*4+lg)^(l15&7) -> 2-way banks (free). XCD-chunked swizzle.
template<int OUTF32>
__global__ __launch_bounds__(256, 2)
void gemm_bt(const unsigned short* __restrict__ A, const unsigned short* __restrict__ BT,
             const float* __restrict__ bias, void* __restrict__ outp,
             int M, int N, int K) {
  const int tid = threadIdx.x;
  const int w = tid >> 6, lane = tid & 63;
  const int lg = lane >> 4, l15 = lane & 15;
  const int wr = w >> 1, wc = w & 1;

  const int nb = gridDim.x * gridDim.y;
  const int fid = blockIdx.y * gridDim.x + blockIdx.x;
  const int swz = (fid & 7) * (nb >> 3) + (fid >> 3);
  const int n0 = (swz % gridDim.x) * 128, m0 = (swz / gridDim.x) * 128;

  __shared__ unsigned short As[128 * 64];
  __shared__ unsigned short Bs[128 * 64];

  f32x4 acc[4][4] = {};

  for (int k0 = 0; k0 < K; k0 += 64) {
    __syncthreads();
#pragma unroll
    for (int i = 0; i < 4; ++i) {
      const int cb = i * 256 + w * 64;   // wave-uniform chunk base
      const int c  = cb + lane;
      const int row = c >> 3, s = c & 7;
      const int sg = s ^ (row & 7);      // pre-swizzled source slot
      GLD16(A  + (size_t)(m0 + row) * K + k0 + sg * 8, (char*)As + cb * 16);
      GLD16(BT + (size_t)(n0 + row) * K + k0 + sg * 8, (char*)Bs + cb * 16);
    }
    __syncthreads();
#pragma unroll
    for (int ks = 0; ks < 2; ++ks) {
      bf16x8 af[4], bfr[4];
#pragma unroll
      for (int mt = 0; mt < 4; ++mt) {
        const int row = wr * 64 + mt * 16 + l15;
        af[mt] = *(const bf16x8*)&As[row * 64 + (((ks * 4 + lg) ^ (l15 & 7)) << 3)];
      }
#pragma unroll
      for (int nt = 0; nt < 4; ++nt) {
        const int row = wc * 64 + nt * 16 + l15;
        bfr[nt] = *(const bf16x8*)&Bs[row * 64 + (((ks * 4 + lg) ^ (l15 & 7)) << 3)];
      }
#pragma unroll
      for (int mt = 0; mt < 4; ++mt)
#pragma unroll
        for (int nt = 0; nt < 4; ++nt)
          acc[mt][nt] = __builtin_amdgcn_mfma_f32_16x16x32_bf16(af[mt], bfr[nt], acc[mt][nt], 0, 0, 0);
    }
  }

#pragma unroll
  for (int mt = 0; mt < 4; ++mt) {
#pragma unroll
    for (int nt = 0; nt < 4; ++nt) {
      const int col = n0 + wc * 64 + nt * 16 + l15;
      const float bv = bias[col];
#pragma unroll
      for (int j = 0; j < 4; ++j) {
        const int row = m0 + wr * 64 + mt * 16 + lg * 4 + j;
        const float v = acc[mt][nt][j] + bv;
        if (OUTF32) ((float*)outp)[(size_t)row * N + col] = v;
        else ((unsigned short*)outp)[(size_t)row * N + col] = f2bf(v);
      }
    }
  }
}

// ---------------- causal flash attention (v5 exact, proven 87.4 us) ----------------
// 512 threads = 8 waves x 16 q-rows; in-block pairing {p,15-p}: uniform 34 KV64 iters.
// K rows bit-permuted in LDS so swapped-QK^T output == PV A-fragment (reg-only P);
// lsum via ones-MFMA in O layout; scalarized mask; K slot swizzle; V chunk swizzle.
#define EXPC 0.18033688f   /* 0.125 * log2(e) */
__global__ __launch_bounds__(512, 4)
void attn_causal5(const unsigned short* __restrict__ qkv, unsigned short* __restrict__ att) {
  const int tid = threadIdx.x;
  const int w = tid >> 6, lane = tid & 63;
  const int lg = lane >> 4, l15 = lane & 15;

  const int fid = blockIdx.x;                   // 0..511
  const int f2 = (fid & 7) * 64 + (fid >> 3);   // XCD-chunked remap (bijective)
  const int pair = f2 & 7, bh = f2 >> 3;
  const int b = bh >> 4, h = bh & 15;

  __shared__ unsigned short Kl[2][2][64][32];   // [buf][kc][ldsrow][el], slot+row permuted
  __shared__ unsigned short Vt[2][64][64];      // [buf][d][kv], chunk-swizzled

  const unsigned short* base = qkv + (size_t)b * T_SEQ * 3072;

  auto STAGE_K = [&](int kv0, int buf) {
    const int c = tid;                          // 512 chunks of 16B
    const int kc = c >> 8, slot = (c >> 2) & 63;
    const int s2 = (c & 3) ^ ((slot >> 1) & 3);
    const int v = (slot & 35) | ((slot & 8) << 1) | ((slot & 4) << 1) | ((slot & 16) >> 2);
    GLD16(base + (size_t)(kv0 + v) * 3072 + 1024 + h * 64 + kc * 32 + s2 * 8,
          (char*)&Kl[buf][0][0][0] + w * 1024);
  };

  bf16x4 vra, vrb;
  const int vkp = tid >> 4, vd4 = tid & 15;
  auto VLOAD = [&](int kv0) {
    const unsigned short* p = base + (size_t)(kv0 + 2 * vkp) * 3072 + 2048 + h * 64 + vd4 * 4;
    vra = *(const bf16x4*)p;
    vrb = *(const bf16x4*)(p + 3072);
  };
  auto VWRITE = [&](int buf) {
    const int ch = vkp >> 2, cl = (vkp & 3) * 2;
#pragma unroll
    for (int j = 0; j < 4; ++j) {
      const int r = vd4 * 4 + j;
      const unsigned int u = (unsigned short)vra[j] |
                             ((unsigned int)(unsigned short)vrb[j] << 16);
      *(unsigned int*)&Vt[buf][r][((ch ^ (r >> 3) ^ (r & 7)) << 3) + cl] = u;
    }
  };

  bf16x8 ones;
#pragma unroll
  for (int j = 0; j < 8; ++j) ones[j] = (short)0x3F80;   // bf16 1.0

  for (int half = 0; half < 2; ++half) {
    const int qt = half ? (15 - pair) : pair;
    const int q0 = qt << 7;
    const int ntl = (qt + 1) << 1;              // KV64 tiles
    const int qminS = __builtin_amdgcn_readfirstlane(q0 + w * 16);
    const int qme = qminS + l15;

    bf16x8 qf[2];
#pragma unroll
    for (int kc = 0; kc < 2; ++kc)
      qf[kc] = *(const bf16x8*)(base + (size_t)qme * 3072 + h * 64 + kc * 32 + lg * 8);

    f32x4 oacc[4] = {};
    f32x4 lsum = {};
    float m = -1e30f;

    STAGE_K(0, 0);
    VLOAD(0);
    VWRITE(0);
    __syncthreads();

    for (int t = 0; t < ntl; ++t) {
      const int cur = t & 1, nxt = cur ^ 1;
      const bool pf = (t + 1) < ntl;
      if (pf) { STAGE_K((t + 1) << 6, nxt); VLOAD((t + 1) << 6); }
      const int kv0 = t << 6;

      if (kv0 <= qminS + 15) {                  // wave has unmasked work
        const int ksl = (lg ^ ((l15 >> 1) & 3)) * 8;
        f32x4 sc[4];
        __builtin_amdgcn_s_setprio(1);
#pragma unroll
        for (int kg = 0; kg < 4; ++kg) {
          f32x4 s = {};
#pragma unroll
          for (int kc = 0; kc < 2; ++kc) {
            bf16x8 kf = *(const bf16x8*)&Kl[cur][kc][kg * 16 + l15][ksl];
            s = __builtin_amdgcn_mfma_f32_16x16x32_bf16(kf, qf[kc], s, 0, 0, 0);
          }
          sc[kg] = s;
        }
        __builtin_amdgcn_s_setprio(0);

        // ---- mask (diagonal tiles only, scalar-guarded) ----
        float sv[4][4];
        if (kv0 + 63 > qminS) {
#pragma unroll
          for (int kg = 0; kg < 4; ++kg) {
            const int colb = kv0 + ((kg >> 1) << 5) + ((kg & 1) << 2) + lg * 8;
#pragma unroll
            for (int j = 0; j < 4; ++j)
              sv[kg][j] = (colb + j <= qme) ? sc[kg][j] : -1e30f;
          }
        } else {
#pragma unroll
          for (int kg = 0; kg < 4; ++kg)
#pragma unroll
            for (int j = 0; j < 4; ++j) sv[kg][j] = sc[kg][j];
        }

        // ---- tree max ----
        float mx = -1e30f;
#pragma unroll
        for (int kg = 0; kg < 4; ++kg) {
          const float a = fmaxf(sv[kg][0], sv[kg][1]);
          const float c2 = fmaxf(sv[kg][2], sv[kg][3]);
          mx = fmaxf(mx, fmaxf(a, c2));
        }

        // ---- defer-max rescale (rare) ----
        if (__any(mx > m + 55.4f)) {
          float mw = fmaxf(mx, __shfl_xor(mx, 16));
          mw = fmaxf(mw, __shfl_xor(mw, 32));
          const float mnew = fmaxf(m, mw);
          const float alc = exp2f((m - mnew) * EXPC);
          m = mnew;
          float alq[4];
#pragma unroll
          for (int j = 0; j < 4; ++j)
            alq[j] = __shfl(alc, (lane & 48) | (lg * 4 + j));
#pragma unroll
          for (int j = 0; j < 4; ++j) {
            lsum[j] *= alq[j];
#pragma unroll
            for (int dt = 0; dt < 4; ++dt) oacc[dt][j] *= alq[j];
          }
        }

        // ---- exp -> PV A-fragments (registers, same lane) ----
        const float mc = m * EXPC;
        bf16x8 pa[2];
#pragma unroll
        for (int kg = 0; kg < 4; ++kg) {
          const int ks = kg >> 1, off = (kg & 1) * 4;
#pragma unroll
          for (int j = 0; j < 4; ++j) {
            const float p = exp2f(__fmaf_rn(sv[kg][j], EXPC, -mc));
            pa[ks][off + j] = (short)f2bf(p);
          }
        }

        // ---- lsum via ones-MFMA + PV ----
        __builtin_amdgcn_s_setprio(1);
        lsum = __builtin_amdgcn_mfma_f32_16x16x32_bf16(pa[0], ones, lsum, 0, 0, 0);
        lsum = __builtin_amdgcn_mfma_f32_16x16x32_bf16(pa[1], ones, lsum, 0, 0, 0);
#pragma unroll
        for (int dt = 0; dt < 4; ++dt) {
          f32x4 o = oacc[dt];
          const int d = dt * 16 + l15;
          const int gx = (d >> 3) ^ (d & 7);    // V chunk swizzle
#pragma unroll
          for (int ks = 0; ks < 2; ++ks) {
            bf16x8 vb = *(const bf16x8*)&Vt[cur][d][((ks * 4 + lg) ^ gx) << 3];
            o = __builtin_amdgcn_mfma_f32_16x16x32_bf16(pa[ks], vb, o, 0, 0, 0);
          }
          oacc[dt] = o;
        }
        __builtin_amdgcn_s_setprio(0);
      }

      if (pf) VWRITE(nxt);
      __syncthreads();   // drains vmcnt (K gld_lds) + lgkm (V writes); swap buffers
    }

    // ---- epilogue: normalize via rcp, store ----
    f32x4 inv;
#pragma unroll
    for (int j = 0; j < 4; ++j) inv[j] = __builtin_amdgcn_rcpf(lsum[j]);
#pragma unroll
    for (int dt = 0; dt < 4; ++dt)
#pragma unroll
      for (int j = 0; j < 4; ++j) {
        const int q = qminS + lg * 4 + j;
        att[(size_t)(b * T_SEQ + q) * CDIM + h * HDIM + dt * 16 + l15] =
            f2bf(oacc[dt][j] * inv[j]);
      }
  }
}

// ---------------- launcher ----------------
extern "C" void kernel_launch(void* const* d_in, const int* in_sizes, int n_in,
                              void* d_out, int out_size, void* d_ws, size_t ws_size,
                              hipStream_t stream) {
  const float* x      = (const float*)d_in[0];
  const float* w_attn = (const float*)d_in[1];
  const float* b_attn = (const float*)d_in[2];
  const float* w_proj = (const float*)d_in[3];
  const float* b_proj = (const float*)d_in[4];

  char* ws = (char*)d_ws;
  unsigned short* xb  = (unsigned short*)(ws + 0);           // 8192*1024 bf16
  unsigned short* wat = (unsigned short*)(ws + 16777216);    // 3072*1024 bf16 (w_attn^T)
  unsigned short* wpt = (unsigned short*)(ws + 23068672);    // 1024*1024 bf16 (w_proj^T)
  unsigned short* qkv = (unsigned short*)(ws + 25165824);    // 8192*3072 bf16
  unsigned short* att = (unsigned short*)(ws + 75497472);    // 8192*1024 bf16

  prep_all<<<dim3(12288), 256, 0, stream>>>(x, w_attn, w_proj, xb, wat, wpt);
  gemm_bt<0><<<dim3(24, 64), 256, 0, stream>>>(xb, wat, b_attn, (void*)qkv, 8192, 3072, 1024);
  attn_causal5<<<dim3(512), 512, 0, stream>>>(qkv, att);
  gemm_bt<1><<<dim3(8, 64), 256, 0, stream>>>(att, wpt, b_proj, d_out, 8192, 1024, 1024);
}